// Round 11
// baseline (1374.950 us; speedup 1.0000x reference)
//
#include <hip/hip_runtime.h>
#include <math.h>

#define BB 8
#define TT 16
#define SS 400
#define HH 512
#define EE 128
#define VV 50000
#define VE 50050
#define OOVn 50

// output offsets (floats)
#define O1 6406400
#define O2 6410496
#define O3 6414592
#define O4 6418688
#define O5 6469888
#define O6 6469896

// scratch inside out0 logits region (float offsets; dead until gemm_logits)
#define G_OFF    0          // 2048x1152 ushort = 1,179,648 f
#define EWHB_OFF 1179648    // 512x512  ushort = 131,072 f -> ends 1,310,720
#define AWBF_OFF 1310720    // 512x1024 ushort = 262,144 f -> ends 1,572,864
#define ENCP_OFF 4600000    // 3200x512 ushort = 409,600 f -> ends 5,009,600
#define PM_OFF   5700000    // 16x8x400 fp32 = 51,200 f -> ends 5,751,200
#define CTXR_OFF 5800000    // 128x512 fp32 raw ctx = 65,536 f -> ends 5,865,536

typedef __attribute__((ext_vector_type(4))) float floatx4;
typedef __attribute__((ext_vector_type(8))) short short8;
typedef __attribute__((ext_vector_type(8))) unsigned short ushort8_t;
typedef __attribute__((ext_vector_type(4))) unsigned short ushort4_t;

__device__ __forceinline__ float sigm(float x){ return 1.0f/(1.0f+__expf(-x)); }
__device__ __forceinline__ float ftanh(float x){
  float e = __expf(2.0f*x); return 1.0f - 2.0f/(e + 1.0f);
}
__device__ __forceinline__ unsigned short f2bf(float f){
  union { float f; unsigned int u; } v; v.f = f;
  unsigned int u = v.u;
  return (unsigned short)((u + 0x7FFFu + ((u >> 16) & 1u)) >> 16);
}
__device__ __forceinline__ float bfu(unsigned short u){
  union { unsigned int i; float f; } v; v.i = ((unsigned int)u) << 16; return v.f;
}
__device__ __forceinline__ float mac8(const unsigned short* w, const float* u) {
  ushort8_t w8 = *(const ushort8_t*)w;
  float4 u0 = *(const float4*)u;
  float4 u1 = *(const float4*)(u+4);
  return bfu(w8[0])*u0.x + bfu(w8[1])*u0.y + bfu(w8[2])*u0.z + bfu(w8[3])*u0.w
       + bfu(w8[4])*u1.x + bfu(w8[5])*u1.y + bfu(w8[6])*u1.z + bfu(w8[7])*u1.w;
}

// ---------------------------------------------------------------------------
// GEMM: C[M,N] = A[M,K] @ B[N,K]^T (+bias). fp32 in, bf16 MFMA, fp32/bf16 out.
// ---------------------------------------------------------------------------
__global__ __launch_bounds__(256)
void gemm_bt(const float* __restrict__ A, int lda,
             const float* __restrict__ Bm, int ldb,
             const float* __restrict__ bias,
             float* __restrict__ Cm, int ldc,
             int N, int K, int permute, int obf,
             long bsB, long bsC)
{
  __shared__ unsigned short Ash[128*72];
  __shared__ unsigned short Bsh[64*72];
  int tid = threadIdx.x;
  int mbase = blockIdx.x * 128;
  int nbase = blockIdx.y * 64;
  long z = blockIdx.z;
  const float* Bz = Bm + z*bsB;
  int wave = tid >> 6, lane = tid & 63;
  int wm = (wave & 1) * 64, wn = (wave >> 1) * 32;
  int fl = lane & 15, quad = lane >> 4;

  floatx4 acc[4][2];
  for (int i=0;i<4;i++) for(int j=0;j<2;j++) acc[i][j] = (floatx4)(0.0f);

  for (int kc = 0; kc < K; kc += 64) {
    float4 ra[8], rb[4];
#pragma unroll
    for (int i = 0; i < 8; ++i) {
      int idx = tid + i*256;
      int row = idx >> 4;
      int c4 = (idx & 15) << 2;
      ra[i] = *(const float4*)(A + (size_t)(mbase+row)*lda + kc + c4);
    }
#pragma unroll
    for (int i = 0; i < 4; ++i) {
      int idx = tid + i*256;
      int row = idx >> 4;
      int c4 = (idx & 15) << 2;
      int gn = nbase + row;
      if (gn < N) rb[i] = *(const float4*)(Bz + (size_t)gn*ldb + kc + c4);
      else { rb[i].x = 0.f; rb[i].y = 0.f; rb[i].z = 0.f; rb[i].w = 0.f; }
    }
    __syncthreads();
#pragma unroll
    for (int i = 0; i < 8; ++i) {
      int idx = tid + i*256;
      int o = (idx >> 4)*72 + ((idx & 15) << 2);
      Ash[o+0]=f2bf(ra[i].x); Ash[o+1]=f2bf(ra[i].y); Ash[o+2]=f2bf(ra[i].z); Ash[o+3]=f2bf(ra[i].w);
    }
#pragma unroll
    for (int i = 0; i < 4; ++i) {
      int idx = tid + i*256;
      int o = (idx >> 4)*72 + ((idx & 15) << 2);
      Bsh[o+0]=f2bf(rb[i].x); Bsh[o+1]=f2bf(rb[i].y); Bsh[o+2]=f2bf(rb[i].z); Bsh[o+3]=f2bf(rb[i].w);
    }
    __syncthreads();
#pragma unroll
    for (int ks = 0; ks < 2; ++ks) {
      short8 af[4], bfr[2];
      int ko = ks*32 + quad*8;
#pragma unroll
      for (int i=0;i<4;i++) af[i]  = *(const short8*)&Ash[(wm + i*16 + fl)*72 + ko];
#pragma unroll
      for (int j=0;j<2;j++) bfr[j] = *(const short8*)&Bsh[(wn + j*16 + fl)*72 + ko];
#pragma unroll
      for (int i=0;i<4;i++)
#pragma unroll
        for (int j=0;j<2;j++)
          acc[i][j] = __builtin_amdgcn_mfma_f32_16x16x32_bf16(af[i], bfr[j], acc[i][j], 0,0,0);
    }
    __syncthreads();
  }
  for (int i=0;i<4;i++){
    for (int j=0;j<2;j++){
      int nc = nbase + wn + j*16 + fl;
      if (nc >= N) continue;
      float bv = bias ? bias[nc] : 0.0f;
      for (int r=0;r<4;r++){
        int mg = mbase + wm + i*16 + quad*4 + r;
        int orow = permute ? ((mg & 7)*16 + (mg >> 3)) : mg;
        float v = acc[i][j][r] + bv;
        long ci = (long)orow*ldc + nc + z*bsC;
        if (obf) ((unsigned short*)Cm)[ci] = f2bf(v);
        else     Cm[ci] = v;
      }
    }
  }
}

// ---------------------------------------------------------------------------
// gemm_logits (R0 structure - confirmed best): 64-col tiles, grid 782.
// ---------------------------------------------------------------------------
__global__ __launch_bounds__(256)
void gemm_logits(const unsigned short* __restrict__ Abf,
                 const float* __restrict__ Bm, const float* __restrict__ bias,
                 float* __restrict__ out, float* __restrict__ rowsum)
{
  __shared__ unsigned short Ash[128*72];
  __shared__ unsigned short Bsh[64*72];
  __shared__ float rowpart[128];
  int tid = threadIdx.x;
  int nbase = blockIdx.x * 64;
  int wave = tid >> 6, lane = tid & 63;
  int wm = (wave & 1) * 64, wn = (wave >> 1) * 32;
  int fl = lane & 15, quad = lane >> 4;

  floatx4 acc[4][2];
  for (int i=0;i<4;i++) for(int j=0;j<2;j++) acc[i][j] = (floatx4)(0.0f);
  if (tid < 128) rowpart[tid] = 0.f;

  for (int kc = 0; kc < 512; kc += 64) {
    ushort8_t raa[4];
    float4 rb[4];
#pragma unroll
    for (int i = 0; i < 4; ++i) {
      int idx = tid + i*256;
      int row = idx >> 3;
      int c8 = (idx & 7) << 3;
      raa[i] = *(const ushort8_t*)(Abf + (size_t)row*512 + kc + c8);
    }
#pragma unroll
    for (int i = 0; i < 4; ++i) {
      int idx = tid + i*256;
      int row = idx >> 4;
      int c4 = (idx & 15) << 2;
      int gn = nbase + row;
      if (gn < VV) rb[i] = *(const float4*)(Bm + (size_t)gn*512 + kc + c4);
      else { rb[i].x = 0.f; rb[i].y = 0.f; rb[i].z = 0.f; rb[i].w = 0.f; }
    }
    __syncthreads();
#pragma unroll
    for (int i = 0; i < 4; ++i) {
      int idx = tid + i*256;
      int o = (idx >> 3)*72 + ((idx & 7) << 3);
      *(ushort8_t*)&Ash[o] = raa[i];
    }
#pragma unroll
    for (int i = 0; i < 4; ++i) {
      int idx = tid + i*256;
      int o = (idx >> 4)*72 + ((idx & 15) << 2);
      Bsh[o+0]=f2bf(rb[i].x); Bsh[o+1]=f2bf(rb[i].y); Bsh[o+2]=f2bf(rb[i].z); Bsh[o+3]=f2bf(rb[i].w);
    }
    __syncthreads();
#pragma unroll
    for (int ks = 0; ks < 2; ++ks) {
      short8 af[4], bfr[2];
      int ko = ks*32 + quad*8;
#pragma unroll
      for (int i=0;i<4;i++) af[i]  = *(const short8*)&Ash[(wm + i*16 + fl)*72 + ko];
#pragma unroll
      for (int j=0;j<2;j++) bfr[j] = *(const short8*)&Bsh[(wn + j*16 + fl)*72 + ko];
#pragma unroll
      for (int i=0;i<4;i++)
#pragma unroll
        for (int j=0;j<2;j++)
          acc[i][j] = __builtin_amdgcn_mfma_f32_16x16x32_bf16(af[i], bfr[j], acc[i][j], 0,0,0);
    }
    __syncthreads();
  }
  for (int i=0;i<4;i++){
    for (int r=0;r<4;r++){
      int mg = wm + i*16 + quad*4 + r;
      int orow = (mg & 7)*16 + (mg >> 3);
      float rs = 0.f;
      for (int j=0;j<2;j++){
        int nc = nbase + wn + j*16 + fl;
        if (nc < VV) {
          float e = __expf(acc[i][j][r] + bias[nc]);
          out[(size_t)orow*VE + nc] = e;
          rs += e;
        }
      }
      atomicAdd(&rowpart[mg], rs);
    }
  }
  __syncthreads();
  if (tid < 128) {
    int orow = (tid & 7)*16 + (tid >> 3);
    atomicAdd(&rowsum[orow], rowpart[tid]);
  }
}

// ---------------------------------------------------------------------------
// vk_attnd: attnd_bf[m][p] = bf16(ab[p] + A1[m,0:1024] . awbf[p,0:1024]).
// ---------------------------------------------------------------------------
__global__ __launch_bounds__(256) void vk_attnd(
    const float* __restrict__ A1, const unsigned short* __restrict__ awbf,
    const float* __restrict__ ab, unsigned short* __restrict__ attnd_bf)
{
  __shared__ float hl[8][1032];
  __shared__ float part[256];
  int tid = threadIdx.x;
  int pc = blockIdx.x & 63;
  int mg = blockIdx.x >> 6;
  int m0 = mg*8;
#pragma unroll
  for (int i = 0; i < 8; ++i)
    *(float4*)&hl[i][tid*4] = *(const float4*)(A1 + (size_t)(m0+i)*1024 + tid*4);
  __syncthreads();
  int dot = tid >> 2, kq = tid & 3;
  int lp = dot >> 3, lm = dot & 7;
  int p = pc*8 + lp;
  const unsigned short* wp = awbf + (size_t)p*1024 + kq*16;
  const float* hh = &hl[lm][kq*16];
  float acc = 0.f;
#pragma unroll
  for (int i = 0; i < 16; ++i) {
    acc += mac8(wp + i*64, hh + i*64);
    acc += mac8(wp + i*64 + 8, hh + i*64 + 8);
  }
  part[tid] = acc;
  __syncthreads();
  if (tid < 64) {
    int lp2 = tid >> 3, lm2 = tid & 7;
    int p2 = pc*8 + lp2;
    float v = ab[p2] + part[tid*4] + part[tid*4+1] + part[tid*4+2] + part[tid*4+3];
    attnd_bf[(size_t)(m0+lm2)*512 + p2] = f2bf(v);
  }
}

// ---------------------------------------------------------------------------
// Prologue P1: G = [Wx = W_ih@xctx_w (640) | W_hh (512)] bf16
// ---------------------------------------------------------------------------
__global__ __launch_bounds__(256) void p_wx(const float* __restrict__ wih,
    const float* __restrict__ whh, const float* __restrict__ xcw,
    unsigned short* __restrict__ G)
{
  int blk = blockIdx.x, tid = threadIdx.x;
  if (blk < 640) {
    int rt = blk / 10, ct = blk % 10;
    __shared__ float wl[32*128];
    __shared__ float xl[128*64];
    for (int i = tid; i < 4096; i += 256) {
      int r = i >> 7, k = i & 127;
      wl[i] = wih[(size_t)(rt*32+r)*128 + k];
    }
    for (int i = tid; i < 8192; i += 256) {
      int e = i >> 6, c = i & 63;
      xl[i] = xcw[(size_t)e*640 + ct*64 + c];
    }
    __syncthreads();
    for (int o = tid; o < 2048; o += 256) {
      int r = o >> 6, c = o & 63;
      float acc = 0.f;
      for (int e = 0; e < 128; ++e) acc += wl[r*128+e]*xl[e*64+c];
      G[(size_t)(rt*32+r)*1152 + ct*64 + c] = f2bf(acc);
    }
  } else {
    int idx = blk - 640;  // 0..511
    for (int q = 0; q < 2; ++q) {
      int n = idx*2048 + q*1024 + tid*4;
      int r = n >> 9, k = n & 511;
      float4 v = *(const float4*)(whh + n);
      ushort4_t s; s[0]=f2bf(v.x); s[1]=f2bf(v.y); s[2]=f2bf(v.z); s[3]=f2bf(v.w);
      *(ushort4_t*)(G + (size_t)r*1152 + 640 + k) = s;
    }
  }
}

// Prologue P2 (+ zero step counters)
__global__ __launch_bounds__(256) void p_small(const float* __restrict__ wih,
    const float* __restrict__ bih, const float* __restrict__ bhh,
    const float* __restrict__ xb, const float* __restrict__ xcw,
    const float* __restrict__ pw, const float* __restrict__ pb,
    float* __restrict__ gb, float* __restrict__ q, float* __restrict__ qb,
    float* __restrict__ d1, float* __restrict__ d2,
    unsigned int* __restrict__ ctr)
{
  int blk = blockIdx.x, tid = threadIdx.x;
  if (blk < 8) {
    __shared__ float xbl[128];
    if (tid < 128) xbl[tid] = xb[tid];
    __syncthreads();
    int r = blk*256 + tid;
    const float* wr = wih + (size_t)r*128;
    float acc = bih[r] + bhh[r];
    for (int e = 0; e < 128; ++e) acc += wr[e]*xbl[e];
    gb[r] = acc;
  } else if (blk < 11) {
    int o = (blk-8)*256 + tid;
    if (o < 640) {
      float acc = 0.f;
      for (int e = 0; e < 128; ++e) acc += pw[1024+e]*xcw[(size_t)e*640 + o];
      q[o] = acc;
    }
  } else {
    if (tid == 0) {
      float acc = 0.f;
      for (int e = 0; e < 128; ++e) acc += pw[1024+e]*xb[e];
      qb[0] = acc + pb[0];
    }
    if (tid < 128) { d1[tid] = 0.f; d2[tid] = 0.f; }
    if (tid < 32) ctr[tid] = 0u;
  }
}

// Prologue P3: ew[:, :512] -> bf16 ; zero ctxraw ; aw -> bf16
__global__ __launch_bounds__(256) void p_cast(const float* __restrict__ ew,
    unsigned short* __restrict__ ewhb, const float* __restrict__ aw,
    unsigned short* __restrict__ awbf, float* __restrict__ ctxraw)
{
  int blk = blockIdx.x, tid = threadIdx.x;
  if (blk < 128) {
    for (int q = 0; q < 2; ++q) {
      size_t n = (size_t)blk*2048 + q*1024 + tid*4;
      int p = (int)(n >> 9), k = (int)(n & 511);
      float4 v = *(const float4*)(ew + (size_t)p*1024 + k);
      ushort4_t s; s[0]=f2bf(v.x); s[1]=f2bf(v.y); s[2]=f2bf(v.z); s[3]=f2bf(v.w);
      *(ushort4_t*)(ewhb + n) = s;
    }
    for (int i = tid; i < 512; i += 256) ctxraw[(size_t)blk*512 + i] = 0.f;
  } else {
    int idx = blk - 128;
    for (int q = 0; q < 4; ++q) {
      size_t n = (size_t)idx*4096 + q*1024 + tid*4;
      float4 v = *(const float4*)(aw + n);
      ushort4_t s; s[0]=f2bf(v.x); s[1]=f2bf(v.y); s[2]=f2bf(v.z); s[3]=f2bf(v.w);
      *(ushort4_t*)(awbf + n) = s;
    }
  }
}

// ---------------------------------------------------------------------------
// step_f: ONE kernel per t-step. 448 blocks (all co-resident: <=38.5KB LDS,
// 256 thr -> >=2 blocks/CU capacity, so no deadlock regardless of order).
//   blocks   0..255: s1g (R4-verified code) -> threadfence -> ctrA++
//   blocks 256..319: spin(ctrA==256) -> s2_hp -> threadfence -> ctrB++
//   blocks 320..447: preload encpb/masks/vvec/covw DURING spin ->
//                    spin(ctrA&&ctrB) -> energies -> PM/d1/d2/ctxraw
// Consumers only wait on lower-ID producers; counters are per-t (no reuse).
// ---------------------------------------------------------------------------
__global__ __launch_bounds__(256) void step_f(
    const unsigned short* __restrict__ G,
    const unsigned short* __restrict__ encpb,
    const unsigned short* __restrict__ ewhb,
    const float* __restrict__ gb,
    const float* __restrict__ emb, const float* __restrict__ context,
    const float* __restrict__ h0, const float* __restrict__ c0,
    const float* __restrict__ coverage, const float* __restrict__ masks,
    const float* __restrict__ enc, const float* __restrict__ vvec,
    const float* __restrict__ covw, const float* __restrict__ eb,
    float* __restrict__ PM, float* __restrict__ d1, float* __restrict__ d2,
    float* __restrict__ ctxraw, float* __restrict__ A1,
    float* __restrict__ c_cur, float* __restrict__ hp,
    float* __restrict__ out,
    unsigned int* __restrict__ ctrA, unsigned int* __restrict__ ctrB, int t)
{
  union ShU {
    struct { float ueh[8][644]; float uc[8][516]; float part[256];
             float gl[64]; float invs[8]; } a;
    struct { float hl[8*516]; float part[256]; } b;
    struct { unsigned short eps[25][512]; float pms[25];
             float red1[4]; float red2[4]; float msk[25]; } c;
  };
  __shared__ ShU sh;
  int tid = threadIdx.x, blk = blockIdx.x;

  if (blk < 256) {
    // ================= stage A: s1g =================
    if (t >= 1 && tid < 8)
      sh.a.invs[tid] = 1.0f / (d2[(t-1)*8 + tid] + 1e-12f*d1[(t-1)*8 + tid]);
    __syncthreads();

    for (int i = 0; i < 5; ++i) {
      int slot = i*256 + tid;
      int b = slot / 160, sl = slot - b*160;
      if (sl < 32) {
        *(float4*)&sh.a.ueh[b][sl*4] = *(const float4*)(emb + (size_t)(b*16+t)*128 + sl*4);
      } else {
        int qq = sl - 32;
        const float* hsrc = t ? (A1 + ((size_t)((t-1)*8+b))*1024) : (h0 + b*512);
        *(float4*)&sh.a.ueh[b][128 + qq*4] = *(const float4*)(hsrc + qq*4);
      }
    }
    for (int i = 0; i < 4; ++i) {
      int slot = i*256 + tid;
      int b = slot >> 7, sl = slot & 127;
      const float* csrc = t ? (ctxraw + ((size_t)((t-1)*8+b))*512)
                            : (context + (size_t)b*512);
      float4 v = *(const float4*)(csrc + sl*4);
      if (t) { float iv = sh.a.invs[b]; v.x*=iv; v.y*=iv; v.z*=iv; v.w*=iv; }
      *(float4*)&sh.a.uc[b][sl*4] = v;
    }
    __syncthreads();

    if (t >= 1 && blk < 8) {
      int b = blk;
      float iv = sh.a.invs[b];
      const float* covprev = (t == 1) ? (coverage + b*400)
                                      : (out + O6 + ((size_t)(b*16 + t-2))*400);
      const float* pmsrc = PM + (size_t)(t-1)*3200 + b*400;
      size_t o = ((size_t)(b*16 + t-1))*400;
      for (int s = tid; s < 400; s += 256) {
        float pr = pmsrc[s] * iv;
        out[O4 + o + s] = pr;
        out[O6 + o + s] = covprev[s] + pr;
      }
    }

    {
      int dot = tid >> 2, kq = tid & 3;
      int rr = dot >> 3, b = dot & 7;
      int gate = rr >> 1, jj = rr & 1;
      int r = gate*512 + blk*2 + jj;
      const unsigned short* gr = G + (size_t)r*1152;
      float acc = 0.f;
      {
        const unsigned short* gp = gr + kq*8;
        const float* up = &sh.a.ueh[b][kq*8];
#pragma unroll
        for (int i = 0; i < 4; ++i) acc += mac8(gp + i*32, up + i*32);
      }
      {
        const unsigned short* gp = gr + 128 + kq*8;
        const float* up = &sh.a.uc[b][kq*8];
#pragma unroll 4
        for (int i = 0; i < 16; ++i) acc += mac8(gp + i*32, up + i*32);
      }
      {
        const unsigned short* gp = gr + 640 + kq*8;
        const float* up = &sh.a.ueh[b][128 + kq*8];
#pragma unroll 4
        for (int i = 0; i < 16; ++i) acc += mac8(gp + i*32, up + i*32);
      }
      sh.a.part[tid] = acc;
    }
    __syncthreads();
    if (tid < 64) {
      int rr2 = tid >> 3;
      int r2 = (rr2 >> 1)*512 + blk*2 + (rr2 & 1);
      sh.a.gl[tid] = sh.a.part[tid*4] + sh.a.part[tid*4+1]
                   + sh.a.part[tid*4+2] + sh.a.part[tid*4+3] + gb[r2];
    }
    __syncthreads();
    if (tid < 16) {
      int jj2 = tid >> 3, b2 = tid & 7;
      float gi = sh.a.gl[(0*2+jj2)*8 + b2];
      float gf = sh.a.gl[(1*2+jj2)*8 + b2];
      float gg = sh.a.gl[(2*2+jj2)*8 + b2];
      float go = sh.a.gl[(3*2+jj2)*8 + b2];
      int j = blk*2 + jj2;
      float cp = t ? c_cur[b2*512+j] : c0[b2*512+j];
      float cn = sigm(gf)*cp + sigm(gi)*ftanh(gg);
      float hn = sigm(go)*ftanh(cn);
      c_cur[b2*512+j] = cn;
      A1[((size_t)(t*8+b2))*1024 + j] = hn;
    }
    __syncthreads();
    __threadfence();
    if (tid == 0) atomicAdd(ctrA, 1u);

  } else if (blk < 320) {
    // ================= stage B: s2_hp (spin on A) =================
    int pc = blk - 256;
    if (tid == 0) {
      while (atomicAdd(ctrA, 0u) < 256u) __builtin_amdgcn_s_sleep(8);
    }
    __syncthreads();
    __threadfence();
    for (int b = 0; b < 8; ++b)
      for (int k = tid; k < 512; k += 256)
        sh.b.hl[b*516 + k] = A1[((size_t)(t*8+b))*1024 + k];
    __syncthreads();
    int dot = tid >> 2, kq = tid & 3;
    int rr = dot >> 3, b = dot & 7;
    int p = pc*8 + rr;
    const unsigned short* wp = ewhb + (size_t)p*512 + kq*16;
    const float* hh = sh.b.hl + b*516 + kq*16;
    float acc = 0.f;
#pragma unroll
    for (int i = 0; i < 8; ++i) {
      acc += mac8(wp + i*64, hh + i*64);
      acc += mac8(wp + i*64 + 8, hh + i*64 + 8);
    }
    sh.b.part[tid] = acc;
    __syncthreads();
    if (tid < 64) {
      int rr2 = tid >> 3, b2 = tid & 7;
      int p2 = pc*8 + rr2;
      hp[b2*512 + p2] = eb[p2] + sh.b.part[tid*4] + sh.b.part[tid*4+1]
                      + sh.b.part[tid*4+2] + sh.b.part[tid*4+3];
    }
    __syncthreads();
    __threadfence();
    if (tid == 0) atomicAdd(ctrB, 1u);

  } else {
    // ================= stage C: energies (spin on A&B) ================
    int bb = (blk - 320) >> 4, sc = (blk - 320) & 15;
    int w = tid >> 6, lane = tid & 63;
    int h0i = lane*8;
    // preload during spin: encpb rows + masks (read-only inputs)
    for (int i = tid; i < 1600; i += 256) {   // 25 rows x 64 ushort8 segs
      int sl = i >> 6, seg = i & 63;
      *(ushort8_t*)&sh.c.eps[sl][seg*8] =
          *(const ushort8_t*)(encpb + ((size_t)(bb*400 + sc*25 + sl))*512 + seg*8);
    }
    if (tid < 25) sh.c.msk[tid] = masks[bb*400 + sc*25 + tid];
    float vv[8], cw[8];
    {
      float4 v0 = *(const float4*)(vvec+h0i), v1 = *(const float4*)(vvec+h0i+4);
      vv[0]=v0.x; vv[1]=v0.y; vv[2]=v0.z; vv[3]=v0.w;
      vv[4]=v1.x; vv[5]=v1.y; vv[6]=v1.z; vv[7]=v1.w;
      float4 c0v = *(const float4*)(covw+h0i), c1v = *(const float4*)(covw+h0i+4);
      cw[0]=c0v.x; cw[1]=c0v.y; cw[2]=c0v.z; cw[3]=c0v.w;
      cw[4]=c1v.x; cw[5]=c1v.y; cw[6]=c1v.z; cw[7]=c1v.w;
    }
    if (tid == 0) {
      while (atomicAdd(ctrA, 0u) < 256u || atomicAdd(ctrB, 0u) < 64u)
        __builtin_amdgcn_s_sleep(8);
    }
    __syncthreads();
    __threadfence();
    float hpv[8];
    {
      const float* hpp = hp + bb*512 + h0i;
      float4 q0 = *(const float4*)(hpp), q1 = *(const float4*)(hpp+4);
      hpv[0]=q0.x; hpv[1]=q0.y; hpv[2]=q0.z; hpv[3]=q0.w;
      hpv[4]=q1.x; hpv[5]=q1.y; hpv[6]=q1.z; hpv[7]=q1.w;
    }
    const float* covp = t ? (out + O6 + ((size_t)(bb*16 + t-1))*400)
                          : (coverage + bb*400);
    float a1s = 0.f, a2s = 0.f;
    for (int sl = w; sl < 25; sl += 4) {
      int s = sc*25 + sl;
      float cv = covp[s];
      ushort8_t e8 = *(const ushort8_t*)&sh.c.eps[sl][h0i];
      float acc = 0.f;
#pragma unroll
      for (int i = 0; i < 8; ++i)
        acc += ftanh(hpv[i] + bfu(e8[i]) + cv*cw[i]) * vv[i];
      for (int off = 32; off > 0; off >>= 1) acc += __shfl_down(acc, off);
      if (lane == 0) {
        float pe = __expf(acc);
        float pmv = pe * sh.c.msk[sl];
        PM[(size_t)t*3200 + bb*400 + s] = pmv;
        sh.c.pms[sl] = pmv;
        a1s += pe; a2s += pmv;
      }
    }
    if (lane == 0) { sh.c.red1[w] = a1s; sh.c.red2[w] = a2s; }
    __syncthreads();
    if (tid == 0) {
      atomicAdd(&d1[t*8+bb], sh.c.red1[0]+sh.c.red1[1]+sh.c.red1[2]+sh.c.red1[3]);
      atomicAdd(&d2[t*8+bb], sh.c.red2[0]+sh.c.red2[1]+sh.c.red2[2]+sh.c.red2[3]);
    }
    {
      float acc0 = 0.f, acc1 = 0.f;
      const float* encb = enc + ((size_t)(bb*400 + sc*25))*512;
#pragma unroll 5
      for (int sl = 0; sl < 25; ++sl) {
        float pmv = sh.c.pms[sl];
        const float* er = encb + (size_t)sl*512;
        acc0 += pmv * er[tid];
        acc1 += pmv * er[tid + 256];
      }
      float* cr = ctxraw + ((size_t)(t*8+bb))*512;
      atomicAdd(&cr[tid], acc0);
      atomicAdd(&cr[tid+256], acc1);
    }
  }
}

// Epilogue (unchanged from R10)
__global__ __launch_bounds__(256) void e_pgen(
    const float* __restrict__ A1f, const float* __restrict__ c_cur,
    const float* __restrict__ emb, const float* __restrict__ context,
    const float* __restrict__ pw, const float* __restrict__ q,
    const float* __restrict__ qb,
    const float* __restrict__ d1, const float* __restrict__ d2,
    const float* __restrict__ ctxraw, const float* __restrict__ PM,
    float* __restrict__ A1, float* __restrict__ pgen,
    float* __restrict__ rowsum, float* __restrict__ out)
{
  int blk = blockIdx.x, tid = threadIdx.x;
  if (blk < 128) {
    int m = blk, t = m >> 3, b = m & 7;
    __shared__ float invT, invP;
    if (tid == 0) invT = 1.0f / (d2[m] + 1e-12f*d1[m]);
    if (tid == 64) invP = t ? 1.0f / (d2[m-8] + 1e-12f*d1[m-8]) : 0.f;
    __syncthreads();
    const float* crT = ctxraw + (size_t)m*512;
    const float* crP = ctxraw + (size_t)(t ? m-8 : m)*512;
    const float* hT   = A1f + (size_t)m*1024;
    const float* embp = emb + (size_t)(b*16+t)*128;
    float acc = 0.f;
    for (int k = tid; k < 512; k += 256) {
      float cT = crT[k] * invT;
      float cP = t ? crP[k] * invP : context[(size_t)b*512 + k];
      acc += pw[k]*cT + pw[512+k]*hT[k] + q[128+k]*cP;
      A1[(size_t)m*1024 + 512 + k] = cT;
    }
    if (tid < 128) acc += q[tid]*embp[tid];
    for (int off = 32; off > 0; off >>= 1) acc += __shfl_down(acc, off);
    __shared__ float red[4];
    if (!(tid & 63)) red[tid>>6] = acc;
    __syncthreads();
    if (tid == 0) {
      float pg = sigm(red[0]+red[1]+red[2]+red[3] + qb[0]);
      pgen[m] = pg;
      if (t == 15) out[O5 + b] = pg;
    }
  } else if (blk == 128) {
    for (int i = tid; i < 4096; i += 256) {
      int b = i >> 9, j = i & 511;
      float inv = 1.0f / (d2[120+b] + 1e-12f*d1[120+b]);
      out[O1 + i] = ctxraw[(size_t)(120+b)*512 + j] * inv;
    }
  } else if (blk == 129) {
    for (int i = tid; i < 4096; i += 256) {
      int b = i >> 9, j = i & 511;
      out[O2 + i] = A1f[((size_t)(120+b))*1024 + j];
    }
  } else if (blk == 130) {
    for (int i = tid; i < 4096; i += 256) out[O3 + i] = c_cur[i];
  } else if (blk == 131) {
    if (tid < 128) rowsum[tid] = 0.f;
  } else {
    int b = blk - 132;
    float inv = 1.0f / (d2[120+b] + 1e-12f*d1[120+b]);
    const float* pmsrc = PM + (size_t)15*3200 + b*400;
    size_t o15 = ((size_t)(b*16 + 15))*400;
    size_t o14 = ((size_t)(b*16 + 14))*400;
    for (int s = tid; s < 400; s += 256) {
      float pr = pmsrc[s] * inv;
      out[O4 + o15 + s] = pr;
      out[O6 + o15 + s] = out[O6 + o14 + s] + pr;
    }
  }
}

// scale + OOV + fused scatter (unchanged from R10)
__global__ __launch_bounds__(256) void k_scale(
    float* __restrict__ out, const float* __restrict__ pgen,
    const float* __restrict__ rowsum, const float* __restrict__ ez,
    const int* __restrict__ extidx)
{
  int orow = blockIdx.x, cy = blockIdx.y, tid = threadIdx.x;
  int b = orow >> 4, t = orow & 15;
  float sc = pgen[t*8+b] / rowsum[orow];
  int c0 = cy*6256;
  int c1 = (cy == 7) ? VE : c0 + 6256;
  float* row = out + (size_t)orow*VE;
  for (int c = c0 + tid*4; c < c1; c += 1024) {
    if (c + 4 <= VV && c + 4 <= c1) {
      float4 v = *(float4*)(row + c);
      v.x *= sc; v.y *= sc; v.z *= sc; v.w *= sc;
      *(float4*)(row + c) = v;
    } else {
      for (int e = 0; e < 4; ++e) {
        int cc2 = c + e;
        if (cc2 < c1) row[cc2] = (cc2 < VV) ? row[cc2]*sc : ez[b*OOVn + cc2 - VV];
      }
    }
  }
  __syncthreads();
  float onem = 1.0f - pgen[t*8+b];
  const float* pr = out + O4 + (size_t)orow*SS;
  for (int s = tid; s < SS; s += 256) {
    int ix = extidx[b*SS + s];
    if (ix >= c0 && ix < c1)
      atomicAdd(&row[ix], onem * pr[s]);
  }
}

extern "C" void kernel_launch(void* const* d_in, const int* in_sizes, int n_in,
                              void* d_out, int out_size, void* d_ws, size_t ws_size,
                              hipStream_t stream)
{
  (void)in_sizes; (void)n_in; (void)out_size; (void)ws_size;
  const float* emb      = (const float*)d_in[0];
  const float* context  = (const float*)d_in[1];
  const float* h0       = (const float*)d_in[2];
  const float* c0       = (const float*)d_in[3];
  const float* enc      = (const float*)d_in[4];
  const float* masks    = (const float*)d_in[5];
  const float* ez       = (const float*)d_in[6];
  const int*   extidx   = (const int*)d_in[7];
  const float* coverage = (const float*)d_in[8];
  const float* wih      = (const float*)d_in[9];
  const float* whh      = (const float*)d_in[10];
  const float* bih      = (const float*)d_in[11];
  const float* bhh      = (const float*)d_in[12];
  const float* covw     = (const float*)d_in[13];
  const float* ew       = (const float*)d_in[14];
  const float* eb       = (const float*)d_in[15];
  const float* vvec     = (const float*)d_in[16];
  const float* xw       = (const float*)d_in[17];
  const float* xb       = (const float*)d_in[18];
  const float* aw       = (const float*)d_in[19];
  const float* ab       = (const float*)d_in[20];
  const float* vw       = (const float*)d_in[21];
  const float* vb       = (const float*)d_in[22];
  const float* pw       = (const float*)d_in[23];
  const float* pb       = (const float*)d_in[24];
  float* out = (float*)d_out;

  float* ws = (float*)d_ws;
  float* A1       = ws;                 // 128 x 1024 [h | ctx]
  float* c_cur    = ws + 131072;        // 4096
  float* hp       = ws + 135168;        // 4096
  unsigned short* attnd_bf = (unsigned short*)(ws + 139264);  // 128x512
  float* pgen     = ws + 172032;        // 128
  float* gb       = ws + 172160;        // 2048
  float* q        = ws + 174208;        // 640
  float* qb       = ws + 174848;        // 1
  float* d1       = ws + 174852;        // 128
  float* d2       = ws + 174980;        // 128
  float* rowsum   = ws + 175108;        // 128
  unsigned int* ctr = (unsigned int*)(ws + 175236);  // 32 (2 per t)

  unsigned short* G     = (unsigned short*)(out + G_OFF);
  unsigned short* ewhb  = (unsigned short*)(out + EWHB_OFF);
  unsigned short* awbf  = (unsigned short*)(out + AWBF_OFF);
  unsigned short* encpb = (unsigned short*)(out + ENCP_OFF);
  float*          PM    = out + PM_OFF;
  float*          ctxr  = out + CTXR_OFF;

  // Prologue
  p_wx<<<1152, 256, 0, stream>>>(wih, whh, xw, G);
  p_small<<<12, 256, 0, stream>>>(wih, bih, bhh, xb, xw, pw, pb, gb, q, qb,
                                  d1, d2, ctr);
  p_cast<<<256, 256, 0, stream>>>(ew, ewhb, aw, awbf, ctxr);
  // encp = enc @ energy_w[:,512:].T  (bf16 out)
  gemm_bt<<<dim3(25,8,1), 256, 0, stream>>>(enc, 512, ew + 512, 1024,
      (const float*)nullptr, (float*)encpb, 512, 512, 512, 0, 1, 0, 0);

  // t-loop: ONE fused kernel per step (448 blocks, internal A->B->C ordering)
  for (int t = 0; t < TT; ++t) {
    step_f<<<448, 256, 0, stream>>>(G, encpb, ewhb, gb, emb, context, h0, c0,
                                    coverage, masks, enc, vvec, covw, eb,
                                    PM, d1, d2, ctxr, A1, c_cur, hp, out,
                                    ctr + 2*t, ctr + 2*t + 1, t);
  }

  e_pgen<<<140, 256, 0, stream>>>(A1, c_cur, emb, context, pw, q, qb,
                                  d1, d2, ctxr, PM, A1, pgen, rowsum, out);
  // attnd_bf = bf16([h|ctx] @ attnd_w.T + attnd_b)  (VALU kernel, 1024 blocks)
  vk_attnd<<<1024, 256, 0, stream>>>(A1, awbf, ab, attnd_bf);
  // logits (R0 structure, 782 blocks)
  gemm_logits<<<782, 256, 0, stream>>>(attnd_bf, vw, vb, out, rowsum);
  // scale + OOV + fused scatter
  k_scale<<<dim3(128,8), 256, 0, stream>>>(out, pgen, rowsum, ez, extidx);
}

// Round 12
// 697.408 us; speedup vs baseline: 1.9715x; 1.9715x over previous
//
#include <hip/hip_runtime.h>
#include <math.h>

#define BB 8
#define TT 16
#define SS 400
#define HH 512
#define EE 128
#define VV 50000
#define VE 50050
#define OOVn 50

// output offsets (floats)
#define O1 6406400
#define O2 6410496
#define O3 6414592
#define O4 6418688
#define O5 6469888
#define O6 6469896

// scratch inside out0 logits region (float offsets; dead until gemm_logits)
#define G_OFF    0          // 2048x1152 ushort = 1,179,648 f
#define EWHB_OFF 1179648    // 512x512  ushort = 131,072 f -> ends 1,310,720
#define AWBF_OFF 1310720    // 512x1024 ushort = 262,144 f -> ends 1,572,864
#define ENCP_OFF 4600000    // 3200x512 ushort = 409,600 f -> ends 5,009,600
#define PM_OFF   5700000    // 16x8x400 fp32 = 51,200 f -> ends 5,751,200
#define CTXR_OFF 5800000    // 128x512 fp32 raw ctx = 65,536 f -> ends 5,865,536

typedef __attribute__((ext_vector_type(4))) float floatx4;
typedef __attribute__((ext_vector_type(8))) short short8;
typedef __attribute__((ext_vector_type(8))) unsigned short ushort8_t;
typedef __attribute__((ext_vector_type(4))) unsigned short ushort4_t;

__device__ __forceinline__ float sigm(float x){ return 1.0f/(1.0f+__expf(-x)); }
__device__ __forceinline__ float ftanh(float x){
  float e = __expf(2.0f*x); return 1.0f - 2.0f/(e + 1.0f);
}
__device__ __forceinline__ unsigned short f2bf(float f){
  union { float f; unsigned int u; } v; v.f = f;
  unsigned int u = v.u;
  return (unsigned short)((u + 0x7FFFu + ((u >> 16) & 1u)) >> 16);
}
__device__ __forceinline__ float bfu(unsigned short u){
  union { unsigned int i; float f; } v; v.i = ((unsigned int)u) << 16; return v.f;
}
__device__ __forceinline__ float mac8(const unsigned short* w, const float* u) {
  ushort8_t w8 = *(const ushort8_t*)w;
  float4 u0 = *(const float4*)u;
  float4 u1 = *(const float4*)(u+4);
  return bfu(w8[0])*u0.x + bfu(w8[1])*u0.y + bfu(w8[2])*u0.z + bfu(w8[3])*u0.w
       + bfu(w8[4])*u1.x + bfu(w8[5])*u1.y + bfu(w8[6])*u1.z + bfu(w8[7])*u1.w;
}

// ---------------------------------------------------------------------------
// GEMM: C[M,N] = A[M,K] @ B[N,K]^T (+bias). fp32 in, bf16 MFMA, fp32/bf16 out.
// ---------------------------------------------------------------------------
__global__ __launch_bounds__(256)
void gemm_bt(const float* __restrict__ A, int lda,
             const float* __restrict__ Bm, int ldb,
             const float* __restrict__ bias,
             float* __restrict__ Cm, int ldc,
             int N, int K, int permute, int obf,
             long bsB, long bsC)
{
  __shared__ unsigned short Ash[128*72];
  __shared__ unsigned short Bsh[64*72];
  int tid = threadIdx.x;
  int mbase = blockIdx.x * 128;
  int nbase = blockIdx.y * 64;
  long z = blockIdx.z;
  const float* Bz = Bm + z*bsB;
  int wave = tid >> 6, lane = tid & 63;
  int wm = (wave & 1) * 64, wn = (wave >> 1) * 32;
  int fl = lane & 15, quad = lane >> 4;

  floatx4 acc[4][2];
  for (int i=0;i<4;i++) for(int j=0;j<2;j++) acc[i][j] = (floatx4)(0.0f);

  for (int kc = 0; kc < K; kc += 64) {
    float4 ra[8], rb[4];
#pragma unroll
    for (int i = 0; i < 8; ++i) {
      int idx = tid + i*256;
      int row = idx >> 4;
      int c4 = (idx & 15) << 2;
      ra[i] = *(const float4*)(A + (size_t)(mbase+row)*lda + kc + c4);
    }
#pragma unroll
    for (int i = 0; i < 4; ++i) {
      int idx = tid + i*256;
      int row = idx >> 4;
      int c4 = (idx & 15) << 2;
      int gn = nbase + row;
      if (gn < N) rb[i] = *(const float4*)(Bz + (size_t)gn*ldb + kc + c4);
      else { rb[i].x = 0.f; rb[i].y = 0.f; rb[i].z = 0.f; rb[i].w = 0.f; }
    }
    __syncthreads();
#pragma unroll
    for (int i = 0; i < 8; ++i) {
      int idx = tid + i*256;
      int o = (idx >> 4)*72 + ((idx & 15) << 2);
      Ash[o+0]=f2bf(ra[i].x); Ash[o+1]=f2bf(ra[i].y); Ash[o+2]=f2bf(ra[i].z); Ash[o+3]=f2bf(ra[i].w);
    }
#pragma unroll
    for (int i = 0; i < 4; ++i) {
      int idx = tid + i*256;
      int o = (idx >> 4)*72 + ((idx & 15) << 2);
      Bsh[o+0]=f2bf(rb[i].x); Bsh[o+1]=f2bf(rb[i].y); Bsh[o+2]=f2bf(rb[i].z); Bsh[o+3]=f2bf(rb[i].w);
    }
    __syncthreads();
#pragma unroll
    for (int ks = 0; ks < 2; ++ks) {
      short8 af[4], bfr[2];
      int ko = ks*32 + quad*8;
#pragma unroll
      for (int i=0;i<4;i++) af[i]  = *(const short8*)&Ash[(wm + i*16 + fl)*72 + ko];
#pragma unroll
      for (int j=0;j<2;j++) bfr[j] = *(const short8*)&Bsh[(wn + j*16 + fl)*72 + ko];
#pragma unroll
      for (int i=0;i<4;i++)
#pragma unroll
        for (int j=0;j<2;j++)
          acc[i][j] = __builtin_amdgcn_mfma_f32_16x16x32_bf16(af[i], bfr[j], acc[i][j], 0,0,0);
    }
    __syncthreads();
  }
  for (int i=0;i<4;i++){
    for (int j=0;j<2;j++){
      int nc = nbase + wn + j*16 + fl;
      if (nc >= N) continue;
      float bv = bias ? bias[nc] : 0.0f;
      for (int r=0;r<4;r++){
        int mg = mbase + wm + i*16 + quad*4 + r;
        int orow = permute ? ((mg & 7)*16 + (mg >> 3)) : mg;
        float v = acc[i][j][r] + bv;
        long ci = (long)orow*ldc + nc + z*bsC;
        if (obf) ((unsigned short*)Cm)[ci] = f2bf(v);
        else     Cm[ci] = v;
      }
    }
  }
}

// ---------------------------------------------------------------------------
// gemm_logits (R0 structure - confirmed best): 64-col tiles, grid 782.
// ---------------------------------------------------------------------------
__global__ __launch_bounds__(256)
void gemm_logits(const unsigned short* __restrict__ Abf,
                 const float* __restrict__ Bm, const float* __restrict__ bias,
                 float* __restrict__ out, float* __restrict__ rowsum)
{
  __shared__ unsigned short Ash[128*72];
  __shared__ unsigned short Bsh[64*72];
  __shared__ float rowpart[128];
  int tid = threadIdx.x;
  int nbase = blockIdx.x * 64;
  int wave = tid >> 6, lane = tid & 63;
  int wm = (wave & 1) * 64, wn = (wave >> 1) * 32;
  int fl = lane & 15, quad = lane >> 4;

  floatx4 acc[4][2];
  for (int i=0;i<4;i++) for(int j=0;j<2;j++) acc[i][j] = (floatx4)(0.0f);
  if (tid < 128) rowpart[tid] = 0.f;

  for (int kc = 0; kc < 512; kc += 64) {
    ushort8_t raa[4];
    float4 rb[4];
#pragma unroll
    for (int i = 0; i < 4; ++i) {
      int idx = tid + i*256;
      int row = idx >> 3;
      int c8 = (idx & 7) << 3;
      raa[i] = *(const ushort8_t*)(Abf + (size_t)row*512 + kc + c8);
    }
#pragma unroll
    for (int i = 0; i < 4; ++i) {
      int idx = tid + i*256;
      int row = idx >> 4;
      int c4 = (idx & 15) << 2;
      int gn = nbase + row;
      if (gn < VV) rb[i] = *(const float4*)(Bm + (size_t)gn*512 + kc + c4);
      else { rb[i].x = 0.f; rb[i].y = 0.f; rb[i].z = 0.f; rb[i].w = 0.f; }
    }
    __syncthreads();
#pragma unroll
    for (int i = 0; i < 4; ++i) {
      int idx = tid + i*256;
      int o = (idx >> 3)*72 + ((idx & 7) << 3);
      *(ushort8_t*)&Ash[o] = raa[i];
    }
#pragma unroll
    for (int i = 0; i < 4; ++i) {
      int idx = tid + i*256;
      int o = (idx >> 4)*72 + ((idx & 15) << 2);
      Bsh[o+0]=f2bf(rb[i].x); Bsh[o+1]=f2bf(rb[i].y); Bsh[o+2]=f2bf(rb[i].z); Bsh[o+3]=f2bf(rb[i].w);
    }
    __syncthreads();
#pragma unroll
    for (int ks = 0; ks < 2; ++ks) {
      short8 af[4], bfr[2];
      int ko = ks*32 + quad*8;
#pragma unroll
      for (int i=0;i<4;i++) af[i]  = *(const short8*)&Ash[(wm + i*16 + fl)*72 + ko];
#pragma unroll
      for (int j=0;j<2;j++) bfr[j] = *(const short8*)&Bsh[(wn + j*16 + fl)*72 + ko];
#pragma unroll
      for (int i=0;i<4;i++)
#pragma unroll
        for (int j=0;j<2;j++)
          acc[i][j] = __builtin_amdgcn_mfma_f32_16x16x32_bf16(af[i], bfr[j], acc[i][j], 0,0,0);
    }
    __syncthreads();
  }
  for (int i=0;i<4;i++){
    for (int r=0;r<4;r++){
      int mg = wm + i*16 + quad*4 + r;
      int orow = (mg & 7)*16 + (mg >> 3);
      float rs = 0.f;
      for (int j=0;j<2;j++){
        int nc = nbase + wn + j*16 + fl;
        if (nc < VV) {
          float e = __expf(acc[i][j][r] + bias[nc]);
          out[(size_t)orow*VE + nc] = e;
          rs += e;
        }
      }
      atomicAdd(&rowpart[mg], rs);
    }
  }
  __syncthreads();
  if (tid < 128) {
    int orow = (tid & 7)*16 + (tid >> 3);
    atomicAdd(&rowsum[orow], rowpart[tid]);
  }
}

// ---------------------------------------------------------------------------
// vk_attnd: attnd_bf[m][p] = bf16(ab[p] + A1[m,0:1024] . awbf[p,0:1024]).
// ---------------------------------------------------------------------------
__global__ __launch_bounds__(256) void vk_attnd(
    const float* __restrict__ A1, const unsigned short* __restrict__ awbf,
    const float* __restrict__ ab, unsigned short* __restrict__ attnd_bf)
{
  __shared__ float hl[8][1032];
  __shared__ float part[256];
  int tid = threadIdx.x;
  int pc = blockIdx.x & 63;
  int mg = blockIdx.x >> 6;
  int m0 = mg*8;
#pragma unroll
  for (int i = 0; i < 8; ++i)
    *(float4*)&hl[i][tid*4] = *(const float4*)(A1 + (size_t)(m0+i)*1024 + tid*4);
  __syncthreads();
  int dot = tid >> 2, kq = tid & 3;
  int lp = dot >> 3, lm = dot & 7;
  int p = pc*8 + lp;
  const unsigned short* wp = awbf + (size_t)p*1024 + kq*16;
  const float* hh = &hl[lm][kq*16];
  float acc = 0.f;
#pragma unroll
  for (int i = 0; i < 16; ++i) {
    acc += mac8(wp + i*64, hh + i*64);
    acc += mac8(wp + i*64 + 8, hh + i*64 + 8);
  }
  part[tid] = acc;
  __syncthreads();
  if (tid < 64) {
    int lp2 = tid >> 3, lm2 = tid & 7;
    int p2 = pc*8 + lp2;
    float v = ab[p2] + part[tid*4] + part[tid*4+1] + part[tid*4+2] + part[tid*4+3];
    attnd_bf[(size_t)(m0+lm2)*512 + p2] = f2bf(v);
  }
}

// ---------------------------------------------------------------------------
// Prologue P1: G = [Wx = W_ih@xctx_w (640) | W_hh (512)] bf16
// ---------------------------------------------------------------------------
__global__ __launch_bounds__(256) void p_wx(const float* __restrict__ wih,
    const float* __restrict__ whh, const float* __restrict__ xcw,
    unsigned short* __restrict__ G)
{
  int blk = blockIdx.x, tid = threadIdx.x;
  if (blk < 640) {
    int rt = blk / 10, ct = blk % 10;
    __shared__ float wl[32*128];
    __shared__ float xl[128*64];
    for (int i = tid; i < 4096; i += 256) {
      int r = i >> 7, k = i & 127;
      wl[i] = wih[(size_t)(rt*32+r)*128 + k];
    }
    for (int i = tid; i < 8192; i += 256) {
      int e = i >> 6, c = i & 63;
      xl[i] = xcw[(size_t)e*640 + ct*64 + c];
    }
    __syncthreads();
    for (int o = tid; o < 2048; o += 256) {
      int r = o >> 6, c = o & 63;
      float acc = 0.f;
      for (int e = 0; e < 128; ++e) acc += wl[r*128+e]*xl[e*64+c];
      G[(size_t)(rt*32+r)*1152 + ct*64 + c] = f2bf(acc);
    }
  } else {
    int idx = blk - 640;  // 0..511
    for (int q = 0; q < 2; ++q) {
      int n = idx*2048 + q*1024 + tid*4;
      int r = n >> 9, k = n & 511;
      float4 v = *(const float4*)(whh + n);
      ushort4_t s; s[0]=f2bf(v.x); s[1]=f2bf(v.y); s[2]=f2bf(v.z); s[3]=f2bf(v.w);
      *(ushort4_t*)(G + (size_t)r*1152 + 640 + k) = s;
    }
  }
}

// Prologue P2
__global__ __launch_bounds__(256) void p_small(const float* __restrict__ wih,
    const float* __restrict__ bih, const float* __restrict__ bhh,
    const float* __restrict__ xb, const float* __restrict__ xcw,
    const float* __restrict__ pw, const float* __restrict__ pb,
    float* __restrict__ gb, float* __restrict__ q, float* __restrict__ qb,
    float* __restrict__ d1, float* __restrict__ d2)
{
  int blk = blockIdx.x, tid = threadIdx.x;
  if (blk < 8) {
    __shared__ float xbl[128];
    if (tid < 128) xbl[tid] = xb[tid];
    __syncthreads();
    int r = blk*256 + tid;
    const float* wr = wih + (size_t)r*128;
    float acc = bih[r] + bhh[r];
    for (int e = 0; e < 128; ++e) acc += wr[e]*xbl[e];
    gb[r] = acc;
  } else if (blk < 11) {
    int o = (blk-8)*256 + tid;
    if (o < 640) {
      float acc = 0.f;
      for (int e = 0; e < 128; ++e) acc += pw[1024+e]*xcw[(size_t)e*640 + o];
      q[o] = acc;
    }
  } else {
    if (tid == 0) {
      float acc = 0.f;
      for (int e = 0; e < 128; ++e) acc += pw[1024+e]*xb[e];
      qb[0] = acc + pb[0];
    }
    if (tid < 128) { d1[tid] = 0.f; d2[tid] = 0.f; }
  }
}

// Prologue P3: ew[:, :512] -> bf16 ; zero ctxraw ; aw -> bf16
__global__ __launch_bounds__(256) void p_cast(const float* __restrict__ ew,
    unsigned short* __restrict__ ewhb, const float* __restrict__ aw,
    unsigned short* __restrict__ awbf, float* __restrict__ ctxraw)
{
  int blk = blockIdx.x, tid = threadIdx.x;
  if (blk < 128) {
    for (int q = 0; q < 2; ++q) {
      size_t n = (size_t)blk*2048 + q*1024 + tid*4;
      int p = (int)(n >> 9), k = (int)(n & 511);
      float4 v = *(const float4*)(ew + (size_t)p*1024 + k);
      ushort4_t s; s[0]=f2bf(v.x); s[1]=f2bf(v.y); s[2]=f2bf(v.z); s[3]=f2bf(v.w);
      *(ushort4_t*)(ewhb + n) = s;
    }
    for (int i = tid; i < 512; i += 256) ctxraw[(size_t)blk*512 + i] = 0.f;
  } else {
    int idx = blk - 128;
    for (int q = 0; q < 4; ++q) {
      size_t n = (size_t)idx*4096 + q*1024 + tid*4;
      float4 v = *(const float4*)(aw + n);
      ushort4_t s; s[0]=f2bf(v.x); s[1]=f2bf(v.y); s[2]=f2bf(v.z); s[3]=f2bf(v.w);
      *(ushort4_t*)(awbf + n) = s;
    }
  }
}

// ---------------------------------------------------------------------------
// S1 v2: 512 blocks (one j column each; 2 blocks/CU for latency hiding).
// 8 threads per dot (kq 0..7), 4 G-rows per block. Same math as R4 s1g.
// ---------------------------------------------------------------------------
__global__ __launch_bounds__(256) void s1g(
    const unsigned short* __restrict__ G,
    const float* __restrict__ gb,
    const float* __restrict__ emb, const float* __restrict__ context,
    const float* __restrict__ h0, const float* __restrict__ c0,
    const float* __restrict__ coverage,
    const float* __restrict__ PM, const float* __restrict__ d1,
    const float* __restrict__ d2, const float* __restrict__ ctxraw,
    float* __restrict__ A1, float* __restrict__ c_cur,
    float* __restrict__ out, int t)
{
  __shared__ float ueh[8][644];
  __shared__ float uc[8][516];
  __shared__ float part[256];
  __shared__ float gl[32];
  __shared__ float invs[8];
  int tid = threadIdx.x, blk = blockIdx.x;   // blk = j (0..511)

  if (t >= 1 && tid < 8)
    invs[tid] = 1.0f / (d2[(t-1)*8 + tid] + 1e-12f*d1[(t-1)*8 + tid]);
  __syncthreads();

  for (int i = 0; i < 5; ++i) {
    int slot = i*256 + tid;
    int b = slot / 160, sl = slot - b*160;
    if (sl < 32) {
      *(float4*)&ueh[b][sl*4] = *(const float4*)(emb + (size_t)(b*16+t)*128 + sl*4);
    } else {
      int qq = sl - 32;
      const float* hsrc = t ? (A1 + ((size_t)((t-1)*8+b))*1024) : (h0 + b*512);
      *(float4*)&ueh[b][128 + qq*4] = *(const float4*)(hsrc + qq*4);
    }
  }
  for (int i = 0; i < 4; ++i) {
    int slot = i*256 + tid;
    int b = slot >> 7, sl = slot & 127;
    const float* csrc = t ? (ctxraw + ((size_t)((t-1)*8+b))*512)
                          : (context + (size_t)b*512);
    float4 v = *(const float4*)(csrc + sl*4);
    if (t) { float iv = invs[b]; v.x*=iv; v.y*=iv; v.z*=iv; v.w*=iv; }
    *(float4*)&uc[b][sl*4] = v;
  }
  __syncthreads();

  if (t >= 1 && blk < 8) {
    int b = blk;
    float iv = invs[b];
    const float* covprev = (t == 1) ? (coverage + b*400)
                                    : (out + O6 + ((size_t)(b*16 + t-2))*400);
    const float* pmsrc = PM + (size_t)(t-1)*3200 + b*400;
    size_t o = ((size_t)(b*16 + t-1))*400;
    for (int s = tid; s < 400; s += 256) {
      float pr = pmsrc[s] * iv;
      out[O4 + o + s] = pr;
      out[O6 + o + s] = covprev[s] + pr;
    }
  }

  {
    int kq = tid & 7, dot = tid >> 3;   // dot 0..31
    int gate = dot >> 3, b = dot & 7;
    int r = gate*512 + blk;
    const unsigned short* gr = G + (size_t)r*1152;
    float acc = 0.f;
    // emb part (128): kq*8 + i*64
#pragma unroll
    for (int i = 0; i < 2; ++i)
      acc += mac8(gr + kq*8 + i*64, &ueh[b][kq*8 + i*64]);
    // ctx part (512) via G cols 128..639
#pragma unroll
    for (int i = 0; i < 8; ++i)
      acc += mac8(gr + 128 + kq*8 + i*64, &uc[b][kq*8 + i*64]);
    // h part (512) via G cols 640..1151
#pragma unroll
    for (int i = 0; i < 8; ++i)
      acc += mac8(gr + 640 + kq*8 + i*64, &ueh[b][128 + kq*8 + i*64]);
    part[tid] = acc;
  }
  __syncthreads();
  if (tid < 32) {
    int gate2 = tid >> 3;
    int r2 = gate2*512 + blk;
    float s = part[tid*8] + part[tid*8+1] + part[tid*8+2] + part[tid*8+3]
            + part[tid*8+4] + part[tid*8+5] + part[tid*8+6] + part[tid*8+7];
    gl[tid] = s + gb[r2];
  }
  __syncthreads();
  if (tid < 8) {
    int b2 = tid;
    float gi = gl[0*8 + b2];
    float gf = gl[1*8 + b2];
    float gg = gl[2*8 + b2];
    float go = gl[3*8 + b2];
    int j = blk;
    float cp = t ? c_cur[b2*512+j] : c0[b2*512+j];
    float cn = sigm(gf)*cp + sigm(gi)*ftanh(gg);
    float hn = sigm(go)*ftanh(cn);
    c_cur[b2*512+j] = cn;
    A1[((size_t)(t*8+b2))*1024 + j] = hn;
  }
}

// ---------------------------------------------------------------------------
// S2 v2: 128 blocks (4 p per block; 8 threads per dot). Same math.
// ---------------------------------------------------------------------------
__global__ __launch_bounds__(256) void s2_hp(
    const unsigned short* __restrict__ ewhb, const float* __restrict__ eb,
    const float* __restrict__ A1, float* __restrict__ hp, int t)
{
  __shared__ float hl[8*516];
  __shared__ float part[256];
  int tid = threadIdx.x, pc = blockIdx.x;   // pc 0..127
  for (int b = 0; b < 8; ++b)
    for (int k = tid; k < 512; k += 256)
      hl[b*516 + k] = A1[((size_t)(t*8+b))*1024 + k];
  __syncthreads();
  int kq = tid & 7, dot = tid >> 3;   // dot 0..31
  int rr = dot >> 3, b = dot & 7;     // rr 0..3
  int p = pc*4 + rr;
  const unsigned short* wp = ewhb + (size_t)p*512 + kq*16;
  const float* hh = hl + b*516 + kq*16;
  float acc = 0.f;
#pragma unroll
  for (int i = 0; i < 4; ++i) {
    acc += mac8(wp + i*128, hh + i*128);
    acc += mac8(wp + i*128 + 8, hh + i*128 + 8);
  }
  part[tid] = acc;
  __syncthreads();
  if (tid < 32) {
    int rr2 = tid >> 3, b2 = tid & 7;
    int p2 = pc*4 + rr2;
    float s = part[tid*8] + part[tid*8+1] + part[tid*8+2] + part[tid*8+3]
            + part[tid*8+4] + part[tid*8+5] + part[tid*8+6] + part[tid*8+7];
    hp[b2*512 + p2] = eb[p2] + s;
  }
}

// ---------------------------------------------------------------------------
// S3 v2: 256 blocks (b = blk>>5, 32 s-chunks of 12-13). Same math.
// ---------------------------------------------------------------------------
__global__ __launch_bounds__(256) void s3e(
    const unsigned short* __restrict__ encpb, const float* __restrict__ hp,
    const float* __restrict__ vvec, const float* __restrict__ covw,
    const float* __restrict__ masks, const float* __restrict__ coverage,
    const float* __restrict__ out6v, const float* __restrict__ enc,
    float* __restrict__ PM, float* __restrict__ d1, float* __restrict__ d2,
    float* __restrict__ ctxraw, int t)
{
  int tid = threadIdx.x;
  int b = blockIdx.x >> 5, sc = blockIdx.x & 31;
  int cnt = (sc < 16) ? 13 : 12;
  int s0 = sc*12 + (sc < 16 ? sc : 16);
  int w = tid >> 6, lane = tid & 63;
  int h0i = lane*8;
  __shared__ float red1[4], red2[4];
  __shared__ float pms[13];
  float hpv[8], vv[8], cw[8];
  {
    const float* hpp = hp + b*512 + h0i;
    float4 a0 = *(const float4*)(hpp), a1 = *(const float4*)(hpp+4);
    hpv[0]=a0.x; hpv[1]=a0.y; hpv[2]=a0.z; hpv[3]=a0.w;
    hpv[4]=a1.x; hpv[5]=a1.y; hpv[6]=a1.z; hpv[7]=a1.w;
    float4 v0 = *(const float4*)(vvec+h0i), v1 = *(const float4*)(vvec+h0i+4);
    vv[0]=v0.x; vv[1]=v0.y; vv[2]=v0.z; vv[3]=v0.w;
    vv[4]=v1.x; vv[5]=v1.y; vv[6]=v1.z; vv[7]=v1.w;
    float4 c0v = *(const float4*)(covw+h0i), c1v = *(const float4*)(covw+h0i+4);
    cw[0]=c0v.x; cw[1]=c0v.y; cw[2]=c0v.z; cw[3]=c0v.w;
    cw[4]=c1v.x; cw[5]=c1v.y; cw[6]=c1v.z; cw[7]=c1v.w;
  }
  const float* covp = t ? (out6v + ((size_t)(b*16 + t-1))*400) : (coverage + b*400);
  float a1s = 0.f, a2s = 0.f;
  for (int sl = w; sl < cnt; sl += 4) {
    int s = s0 + sl;
    float cv = covp[s];
    const unsigned short* ep = encpb + ((size_t)(b*400+s))*512 + h0i;
    ushort8_t e8 = *(const ushort8_t*)ep;
    float acc = 0.f;
#pragma unroll
    for (int i = 0; i < 8; ++i)
      acc += ftanh(hpv[i] + bfu(e8[i]) + cv*cw[i]) * vv[i];
    for (int off = 32; off > 0; off >>= 1) acc += __shfl_down(acc, off);
    if (lane == 0) {
      float pe = __expf(acc);
      float pmv = pe * masks[b*400 + s];
      PM[(size_t)t*3200 + b*400 + s] = pmv;
      pms[sl] = pmv;
      a1s += pe; a2s += pmv;
    }
  }
  if (lane == 0) { red1[w] = a1s; red2[w] = a2s; }
  __syncthreads();
  if (tid == 0) {
    atomicAdd(&d1[t*8+b], red1[0]+red1[1]+red1[2]+red1[3]);
    atomicAdd(&d2[t*8+b], red2[0]+red2[1]+red2[2]+red2[3]);
  }
  {
    float acc0 = 0.f, acc1 = 0.f;
    const float* encb = enc + ((size_t)(b*400 + s0))*512;
    for (int sl = 0; sl < cnt; ++sl) {
      float pmv = pms[sl];
      const float* er = encb + (size_t)sl*512;
      acc0 += pmv * er[tid];
      acc1 += pmv * er[tid + 256];
    }
    float* cr = ctxraw + ((size_t)(t*8+b))*512;
    atomicAdd(&cr[tid], acc0);
    atomicAdd(&cr[tid+256], acc1);
  }
}

// Epilogue (unchanged from R10)
__global__ __launch_bounds__(256) void e_pgen(
    const float* __restrict__ A1f, const float* __restrict__ c_cur,
    const float* __restrict__ emb, const float* __restrict__ context,
    const float* __restrict__ pw, const float* __restrict__ q,
    const float* __restrict__ qb,
    const float* __restrict__ d1, const float* __restrict__ d2,
    const float* __restrict__ ctxraw, const float* __restrict__ PM,
    float* __restrict__ A1, float* __restrict__ pgen,
    float* __restrict__ rowsum, float* __restrict__ out)
{
  int blk = blockIdx.x, tid = threadIdx.x;
  if (blk < 128) {
    int m = blk, t = m >> 3, b = m & 7;
    __shared__ float invT, invP;
    if (tid == 0) invT = 1.0f / (d2[m] + 1e-12f*d1[m]);
    if (tid == 64) invP = t ? 1.0f / (d2[m-8] + 1e-12f*d1[m-8]) : 0.f;
    __syncthreads();
    const float* crT = ctxraw + (size_t)m*512;
    const float* crP = ctxraw + (size_t)(t ? m-8 : m)*512;
    const float* hT   = A1f + (size_t)m*1024;
    const float* embp = emb + (size_t)(b*16+t)*128;
    float acc = 0.f;
    for (int k = tid; k < 512; k += 256) {
      float cT = crT[k] * invT;
      float cP = t ? crP[k] * invP : context[(size_t)b*512 + k];
      acc += pw[k]*cT + pw[512+k]*hT[k] + q[128+k]*cP;
      A1[(size_t)m*1024 + 512 + k] = cT;
    }
    if (tid < 128) acc += q[tid]*embp[tid];
    for (int off = 32; off > 0; off >>= 1) acc += __shfl_down(acc, off);
    __shared__ float red[4];
    if (!(tid & 63)) red[tid>>6] = acc;
    __syncthreads();
    if (tid == 0) {
      float pg = sigm(red[0]+red[1]+red[2]+red[3] + qb[0]);
      pgen[m] = pg;
      if (t == 15) out[O5 + b] = pg;
    }
  } else if (blk == 128) {
    for (int i = tid; i < 4096; i += 256) {
      int b = i >> 9, j = i & 511;
      float inv = 1.0f / (d2[120+b] + 1e-12f*d1[120+b]);
      out[O1 + i] = ctxraw[(size_t)(120+b)*512 + j] * inv;
    }
  } else if (blk == 129) {
    for (int i = tid; i < 4096; i += 256) {
      int b = i >> 9, j = i & 511;
      out[O2 + i] = A1f[((size_t)(120+b))*1024 + j];
    }
  } else if (blk == 130) {
    for (int i = tid; i < 4096; i += 256) out[O3 + i] = c_cur[i];
  } else if (blk == 131) {
    if (tid < 128) rowsum[tid] = 0.f;
  } else {
    int b = blk - 132;
    float inv = 1.0f / (d2[120+b] + 1e-12f*d1[120+b]);
    const float* pmsrc = PM + (size_t)15*3200 + b*400;
    size_t o15 = ((size_t)(b*16 + 15))*400;
    size_t o14 = ((size_t)(b*16 + 14))*400;
    for (int s = tid; s < 400; s += 256) {
      float pr = pmsrc[s] * inv;
      out[O4 + o15 + s] = pr;
      out[O6 + o15 + s] = out[O6 + o14 + s] + pr;
    }
  }
}

// scale + OOV + fused scatter (unchanged from R10)
__global__ __launch_bounds__(256) void k_scale(
    float* __restrict__ out, const float* __restrict__ pgen,
    const float* __restrict__ rowsum, const float* __restrict__ ez,
    const int* __restrict__ extidx)
{
  int orow = blockIdx.x, cy = blockIdx.y, tid = threadIdx.x;
  int b = orow >> 4, t = orow & 15;
  float sc = pgen[t*8+b] / rowsum[orow];
  int c0 = cy*6256;
  int c1 = (cy == 7) ? VE : c0 + 6256;
  float* row = out + (size_t)orow*VE;
  for (int c = c0 + tid*4; c < c1; c += 1024) {
    if (c + 4 <= VV && c + 4 <= c1) {
      float4 v = *(float4*)(row + c);
      v.x *= sc; v.y *= sc; v.z *= sc; v.w *= sc;
      *(float4*)(row + c) = v;
    } else {
      for (int e = 0; e < 4; ++e) {
        int cc2 = c + e;
        if (cc2 < c1) row[cc2] = (cc2 < VV) ? row[cc2]*sc : ez[b*OOVn + cc2 - VV];
      }
    }
  }
  __syncthreads();
  float onem = 1.0f - pgen[t*8+b];
  const float* pr = out + O4 + (size_t)orow*SS;
  for (int s = tid; s < SS; s += 256) {
    int ix = extidx[b*SS + s];
    if (ix >= c0 && ix < c1)
      atomicAdd(&row[ix], onem * pr[s]);
  }
}

extern "C" void kernel_launch(void* const* d_in, const int* in_sizes, int n_in,
                              void* d_out, int out_size, void* d_ws, size_t ws_size,
                              hipStream_t stream)
{
  (void)in_sizes; (void)n_in; (void)out_size; (void)ws_size;
  const float* emb      = (const float*)d_in[0];
  const float* context  = (const float*)d_in[1];
  const float* h0       = (const float*)d_in[2];
  const float* c0       = (const float*)d_in[3];
  const float* enc      = (const float*)d_in[4];
  const float* masks    = (const float*)d_in[5];
  const float* ez       = (const float*)d_in[6];
  const int*   extidx   = (const int*)d_in[7];
  const float* coverage = (const float*)d_in[8];
  const float* wih      = (const float*)d_in[9];
  const float* whh      = (const float*)d_in[10];
  const float* bih      = (const float*)d_in[11];
  const float* bhh      = (const float*)d_in[12];
  const float* covw     = (const float*)d_in[13];
  const float* ew       = (const float*)d_in[14];
  const float* eb       = (const float*)d_in[15];
  const float* vvec     = (const float*)d_in[16];
  const float* xw       = (const float*)d_in[17];
  const float* xb       = (const float*)d_in[18];
  const float* aw       = (const float*)d_in[19];
  const float* ab       = (const float*)d_in[20];
  const float* vw       = (const float*)d_in[21];
  const float* vb       = (const float*)d_in[22];
  const float* pw       = (const float*)d_in[23];
  const float* pb       = (const float*)d_in[24];
  float* out = (float*)d_out;

  float* ws = (float*)d_ws;
  float* A1       = ws;                 // 128 x 1024 [h | ctx]
  float* c_cur    = ws + 131072;        // 4096
  float* hp       = ws + 135168;        // 4096
  unsigned short* attnd_bf = (unsigned short*)(ws + 139264);  // 128x512
  float* pgen     = ws + 172032;        // 128
  float* gb       = ws + 172160;        // 2048
  float* q        = ws + 174208;        // 640
  float* qb       = ws + 174848;        // 1
  float* d1       = ws + 174852;        // 128
  float* d2       = ws + 174980;        // 128
  float* rowsum   = ws + 175108;        // 128

  unsigned short* G     = (unsigned short*)(out + G_OFF);
  unsigned short* ewhb  = (unsigned short*)(out + EWHB_OFF);
  unsigned short* awbf  = (unsigned short*)(out + AWBF_OFF);
  unsigned short* encpb = (unsigned short*)(out + ENCP_OFF);
  float*          PM    = out + PM_OFF;
  float*          ctxr  = out + CTXR_OFF;

  // Prologue
  p_wx<<<1152, 256, 0, stream>>>(wih, whh, xw, G);
  p_small<<<12, 256, 0, stream>>>(wih, bih, bhh, xb, xw, pw, pb, gb, q, qb, d1, d2);
  p_cast<<<256, 256, 0, stream>>>(ew, ewhb, aw, awbf, ctxr);
  // encp = enc @ energy_w[:,512:].T  (bf16 out)
  gemm_bt<<<dim3(25,8,1), 256, 0, stream>>>(enc, 512, ew + 512, 1024,
      (const float*)nullptr, (float*)encpb, 512, 512, 512, 0, 1, 0, 0);

  // t-loop: R10 split structure, higher grid parallelism per kernel
  for (int t = 0; t < TT; ++t) {
    s1g<<<512, 256, 0, stream>>>(G, gb, emb, context, h0, c0, coverage,
                                 PM, d1, d2, ctxr, A1, c_cur, out, t);
    s2_hp<<<128, 256, 0, stream>>>(ewhb, eb, A1, hp, t);
    s3e<<<256, 256, 0, stream>>>(encpb, hp, vvec, covw, masks, coverage,
                                 out + O6, enc, PM, d1, d2, ctxr, t);
  }

  e_pgen<<<140, 256, 0, stream>>>(A1, c_cur, emb, context, pw, q, qb,
                                  d1, d2, ctxr, PM, A1, pgen, rowsum, out);
  // attnd_bf = bf16([h|ctx] @ attnd_w.T + attnd_b)  (VALU kernel, 1024 blocks)
  vk_attnd<<<1024, 256, 0, stream>>>(A1, awbf, ab, attnd_bf);
  // logits (R0 structure, 782 blocks)
  gemm_logits<<<782, 256, 0, stream>>>(attnd_bf, vw, vb, out, rowsum);
  // scale + OOV + fused scatter
  k_scale<<<dim3(128,8), 256, 0, stream>>>(out, pgen, rowsum, ez, extidx);
}